// Round 1
// baseline (82.037 us; speedup 1.0000x reference)
//
#include <hip/hip_runtime.h>
#include <hip/hip_bf16.h>
#include <stdint.h>

#define BATCH 256
#define INF   1024
#define OUTF  128
#define KD    8
#define NN    1024   // OUTF*KD
#define OROW  1152   // INF + OUTF

typedef __attribute__((ext_vector_type(8))) short short8;
typedef __attribute__((ext_vector_type(4))) float f32x4;

__device__ __forceinline__ unsigned short f2bf(float f) {
    union { float f; uint32_t u; } v; v.f = f;
    uint32_t r = v.u + 0x7FFFu + ((v.u >> 16) & 1u);   // RNE
    return (unsigned short)(r >> 16);
}

// K1: T transpose-convert (blocks 0..255), x copy + bf16 convert + c-init (blocks 256..319)
__global__ __launch_bounds__(256) void prep_kernel(
    const float* __restrict__ x, const float* __restrict__ T,
    float* __restrict__ out, unsigned short* __restrict__ xbf,
    unsigned short* __restrict__ Tt)
{
    __shared__ unsigned short lds[64 * 65];
    int bid = blockIdx.x;
    int t = threadIdx.x;
    if (bid < 256) {
        // 64x64 tile: read T[i][n] coalesced, write Tt[n][i] coalesced (bf16)
        int i0 = (bid >> 4) << 6;
        int n0 = (bid & 15) << 6;
        int tx = t & 63, ty = t >> 6;
        for (int r = ty; r < 64; r += 4) {
            float v = T[(size_t)(i0 + r) * NN + n0 + tx];
            lds[tx * 65 + r] = f2bf(v);   // lds[n_local][i_local]
        }
        __syncthreads();
        for (int p = 0; p < 8; ++p) {
            int q = p * 512 + t * 2;
            int n = q >> 6, i = q & 63;   // i even
            uint32_t u = (uint32_t)lds[n * 65 + i] | ((uint32_t)lds[n * 65 + i + 1] << 16);
            *(uint32_t*)(Tt + (size_t)(n0 + n) * INF + i0 + i) = u;
        }
    } else {
        int bx = bid - 256;   // 0..63
        for (int p = 0; p < 4; ++p) {
            int a = bx * 4 + p;
            int j = t * 4;
            float4 v = *(const float4*)(x + (size_t)a * INF + j);
            *(float4*)(out + (size_t)a * OROW + j) = v;
            uint2 u;
            u.x = (uint32_t)f2bf(v.x) | ((uint32_t)f2bf(v.y) << 16);
            u.y = (uint32_t)f2bf(v.z) | ((uint32_t)f2bf(v.w) << 16);
            *(uint2*)(xbf + (size_t)a * INF + j) = u;
        }
        // init c region to -1.0 (cancels the self-term exp(0)=1)
        for (int s = t; s < 512; s += 256) {
            int f = bx * 512 + s;
            int a = f >> 7, o = f & 127;
            out[(size_t)a * OROW + INF + o] = -1.0f;
        }
    }
}

// K2: M = x_bf * Tt^T via bf16 MFMA. 256 blocks (8 a-tiles x 32 n-tiles of 32x32),
// 128 threads = 2 waves splitting K, combined through LDS.
__global__ __launch_bounds__(128) void gemm_kernel(
    const unsigned short* __restrict__ xbf,
    const unsigned short* __restrict__ Tt,
    float* __restrict__ M)
{
    __shared__ float lds[64 * 16];
    int bid = blockIdx.x;
    int a0 = (bid & 7) << 5;
    int n0 = (bid >> 3) << 5;
    int t = threadIdx.x;
    int wave = t >> 6, lane = t & 63;
    int rc = lane & 15, quad = lane >> 4;
    int k0 = wave * 512 + quad * 8;

    f32x4 acc[2][2] = {{{0.f,0.f,0.f,0.f},{0.f,0.f,0.f,0.f}},
                       {{0.f,0.f,0.f,0.f},{0.f,0.f,0.f,0.f}}};
    const unsigned short* pa0 = xbf + (size_t)(a0 + rc) * INF + k0;
    const unsigned short* pa1 = pa0 + 16 * INF;
    const unsigned short* pb0 = Tt + (size_t)(n0 + rc) * INF + k0;
    const unsigned short* pb1 = pb0 + 16 * INF;
#pragma unroll 4
    for (int s = 0; s < 16; ++s) {
        int k = s * 32;
        short8 af0 = *(const short8*)(pa0 + k);
        short8 af1 = *(const short8*)(pa1 + k);
        short8 bg0 = *(const short8*)(pb0 + k);
        short8 bg1 = *(const short8*)(pb1 + k);
        acc[0][0] = __builtin_amdgcn_mfma_f32_16x16x32_bf16(af0, bg0, acc[0][0], 0, 0, 0);
        acc[0][1] = __builtin_amdgcn_mfma_f32_16x16x32_bf16(af0, bg1, acc[0][1], 0, 0, 0);
        acc[1][0] = __builtin_amdgcn_mfma_f32_16x16x32_bf16(af1, bg0, acc[1][0], 0, 0, 0);
        acc[1][1] = __builtin_amdgcn_mfma_f32_16x16x32_bf16(af1, bg1, acc[1][1], 0, 0, 0);
    }
    if (wave == 1) {
        for (int h = 0; h < 2; ++h)
            for (int g = 0; g < 2; ++g)
                for (int r = 0; r < 4; ++r)
                    lds[lane * 16 + (h * 2 + g) * 4 + r] = acc[h][g][r];
    }
    __syncthreads();
    if (wave == 0) {
        for (int h = 0; h < 2; ++h)
            for (int g = 0; g < 2; ++g)
                for (int r = 0; r < 4; ++r) {
                    float v = acc[h][g][r] + lds[lane * 16 + (h * 2 + g) * 4 + r];
                    // C/D layout: col = lane&15, row = quad*4 + r  [measured m89/m91]
                    int rr = a0 + h * 16 + quad * 4 + r;
                    int cc = n0 + g * 16 + rc;
                    M[(size_t)rr * NN + cc] = v;
                }
    }
}

// K3: c[a,o] += sum_b exp(-L1(M[a,o,:], M[b,o,:])). 256 blocks = 128 o x 2 b-halves.
__global__ __launch_bounds__(256) void pair_kernel(
    const float* __restrict__ M, float* __restrict__ out)
{
    int o = blockIdx.x >> 1;
    int half = blockIdx.x & 1;
    int a = threadIdx.x;
    const float* ma = M + (size_t)a * NN + o * KD;
    float4 m0 = *(const float4*)(ma);
    float4 m1 = *(const float4*)(ma + 4);
    float ssum = 0.f;
    int b0 = half * 128;
#pragma unroll 4
    for (int b = b0; b < b0 + 128; ++b) {
        const float* mb = M + (size_t)b * NN + o * KD;   // wave-uniform address
        float4 q0 = *(const float4*)(mb);
        float4 q1 = *(const float4*)(mb + 4);
        float d = fabsf(m0.x - q0.x) + fabsf(m0.y - q0.y)
                + fabsf(m0.z - q0.z) + fabsf(m0.w - q0.w)
                + fabsf(m1.x - q1.x) + fabsf(m1.y - q1.y)
                + fabsf(m1.z - q1.z) + fabsf(m1.w - q1.w);
        ssum += __expf(-d);
    }
    atomicAdd(out + (size_t)a * OROW + INF + o, ssum);
}

extern "C" void kernel_launch(void* const* d_in, const int* in_sizes, int n_in,
                              void* d_out, int out_size, void* d_ws, size_t ws_size,
                              hipStream_t stream) {
    const float* x = (const float*)d_in[0];
    const float* T = (const float*)d_in[1];
    float* out = (float*)d_out;
    // ws layout: x_bf [512 KB] | Tt [2 MB] | M [1 MB]
    unsigned short* xbf = (unsigned short*)d_ws;
    unsigned short* Tt  = (unsigned short*)((char*)d_ws + 524288);
    float*          M   = (float*)((char*)d_ws + 524288 + 2097152);

    prep_kernel<<<320, 256, 0, stream>>>(x, T, out, xbf, Tt);
    gemm_kernel<<<256, 128, 0, stream>>>(xbf, Tt, M);
    pair_kernel<<<256, 256, 0, stream>>>(M, out);
}